// Round 8
// baseline (783.592 us; speedup 1.0000x reference)
//
#include <hip/hip_runtime.h>
#include <stdint.h>

static constexpr float EPS = 1e-5f;
static constexpr int XB = 64;   // gram split-K partial blocks

typedef __attribute__((ext_vector_type(8))) short bfrag;
typedef __attribute__((ext_vector_type(4))) float ffrag;

__device__ __forceinline__ float bf2f(unsigned short u){
  union { unsigned int i; float f; } v; v.i = ((unsigned int)u) << 16; return v.f;
}
__device__ __forceinline__ unsigned short f2bf(float f){
  union { float f; unsigned int i; } v; v.f = f;
  unsigned int x = v.i;
  x += 0x7fffu + ((x >> 16) & 1u);   // round-to-nearest-even
  return (unsigned short)(x >> 16);
}
__device__ __forceinline__ float lo16(unsigned int v){ return bf2f((unsigned short)(v & 0xffffu)); }
__device__ __forceinline__ float hi16(unsigned int v){ return bf2f((unsigned short)(v >> 16)); }
__device__ __forceinline__ unsigned int pack2(float a, float b){
  return ((unsigned int)f2bf(b) << 16) | (unsigned int)f2bf(a);
}

// Grid barrier: all blocks co-resident (grid <= guaranteed blocks/CU * 256).
// Device-scope release (threadfence -> L2 writeback) before arrival; acquire
// spin-load (L1/L2 invalidate) before proceeding.
__device__ __forceinline__ void gbar(int* cnt, int target){
  __threadfence();
  __syncthreads();
  if (threadIdx.x == 0){
    __hip_atomic_fetch_add(cnt, 1, __ATOMIC_ACQ_REL, __HIP_MEMORY_SCOPE_AGENT);
    while (__hip_atomic_load(cnt, __ATOMIC_ACQUIRE, __HIP_MEMORY_SCOPE_AGENT) < target){
      __builtin_amdgcn_s_sleep(8);
    }
  }
  __syncthreads();
}

// ---------------- fused graph build: deg+wcast | alloc | scatter+castx ----------------
__global__ __launch_bounds__(256) void k_graph(const int* __restrict__ row, const int* __restrict__ col,
                                               int N, int E,
                                               int* __restrict__ indeg, int* __restrict__ ctr,
                                               int* __restrict__ offs, int* __restrict__ cursor,
                                               float* __restrict__ dinv, int* __restrict__ csr,
                                               const float* __restrict__ x, unsigned short* __restrict__ xs,
                                               const float* __restrict__ W1, const float* __restrict__ W2,
                                               unsigned short* __restrict__ Wt1, unsigned short* __restrict__ Wt2,
                                               int* __restrict__ bars){
  int bid = blockIdx.x;
  int gid = bid * 256 + threadIdx.x;
  int gstride = gridDim.x * 256;
  int target = gridDim.x;

  // phase 0: degree histogram (2 edges/thread) + weight transpose/cast
  for (int e0 = gid * 2; e0 < E; e0 += gstride * 2){
    if (e0 + 1 < E){
      int2 cc = *(const int2*)&col[e0];
      unsigned c0 = (unsigned)cc.x, c1 = (unsigned)cc.y;
      if (c0 < (unsigned)N) atomicAdd(&indeg[c0], 1);
      if (c1 < (unsigned)N) atomicAdd(&indeg[c1], 1);
    } else {
      unsigned c0 = (unsigned)col[e0];
      if (c0 < (unsigned)N) atomicAdd(&indeg[c0], 1);
    }
  }
  for (int idx = gid; idx < 131072; idx += gstride){
    int i2 = idx; const float* W = W1; unsigned short* Wt = Wt1;
    if (i2 >= 65536){ i2 -= 65536; W = W2; Wt = Wt2; }
    int c = i2 >> 7, k = i2 & 127;
    Wt[(size_t)c * 128 + k] = f2bf(W[(size_t)(c >> 7) * 16384 + k * 128 + (c & 127)]);
  }
  gbar(&bars[0], target);

  // phase 1: CSR range allocation (wave-scan + global bump; nondeterministic but valid)
  {
    int wv = threadIdx.x >> 6, lane = threadIdx.x & 63;
    int nwaves = gridDim.x * 4;
    for (int wb = bid * 4 + wv; wb * 64 < N; wb += nwaves){
      int i = wb * 64 + lane;
      int v = (i < N) ? indeg[i] : 0;
      int incl = v;
      #pragma unroll
      for (int d = 1; d < 64; d <<= 1){ int u = __shfl_up(incl, d); if (lane >= d) incl += u; }
      int base = 0;
      if (lane == 63) base = atomicAdd(ctr, incl);
      base = __shfl(base, 63);
      if (i < N){
        int o = base + incl - v;
        offs[i] = o; cursor[i] = o;
        dinv[i] = rsqrtf((float)(v + 1));
      }
    }
  }
  gbar(&bars[1], target);

  // phase 2: CSR scatter + xs = bf16(dinv*x)
  for (int e0 = gid * 2; e0 < E; e0 += gstride * 2){
    #pragma unroll
    for (int q = 0; q < 2; q++){
      int e = e0 + q;
      if (e < E){
        unsigned c = (unsigned)col[e];
        if (c < (unsigned)N){
          int p = atomicAdd(&cursor[c], 1);
          unsigned r = (unsigned)row[e];
          csr[p] = (r < (unsigned)N) ? (int)r : 0;
        }
      }
    }
  }
  int total4x = N * 32;
  for (int idx = gid; idx < total4x; idx += gstride){
    int i = idx >> 5;
    float di = dinv[i];
    float4 v = ((const float4*)x)[idx];
    ushort4 o;
    o.x = f2bf(di * v.x); o.y = f2bf(di * v.y);
    o.z = f2bf(di * v.z); o.w = f2bf(di * v.w);
    ((ushort4*)xs)[idx] = o;
  }
}

// ---------------- s = P x : 1 node/wave, 16-wide unroll ----------------
__global__ __launch_bounds__(256) void k_prop_x(const unsigned int* __restrict__ xs2,
                                               const int* __restrict__ csr,
                                               const int* __restrict__ offs, const int* __restrict__ indeg,
                                               const float* __restrict__ dinv,
                                               unsigned int* __restrict__ s2, int N){
  int i = blockIdx.x * 4 + (threadIdx.x >> 6);
  if (i >= N) return;
  int c2 = threadIdx.x & 63;
  unsigned int sv = xs2[(size_t)i*64 + c2];
  float ax = lo16(sv), ay = hi16(sv);
  int e = offs[i], end = e + indeg[i];
  for (; e + 16 <= end; e += 16){
    int r[16];
    #pragma unroll
    for (int j = 0; j < 16; j++) r[j] = csr[e + j];
    unsigned int v[16];
    #pragma unroll
    for (int j = 0; j < 16; j++) v[j] = xs2[(size_t)r[j]*64 + c2];
    #pragma unroll
    for (int j = 0; j < 16; j++){ ax += lo16(v[j]); ay += hi16(v[j]); }
  }
  for (; e + 4 <= end; e += 4){
    int r0 = csr[e], r1 = csr[e+1], r2 = csr[e+2], r3 = csr[e+3];
    unsigned int v0 = xs2[(size_t)r0*64 + c2], v1 = xs2[(size_t)r1*64 + c2];
    unsigned int v2 = xs2[(size_t)r2*64 + c2], v3 = xs2[(size_t)r3*64 + c2];
    ax += lo16(v0)+lo16(v1)+lo16(v2)+lo16(v3);
    ay += hi16(v0)+hi16(v1)+hi16(v2)+hi16(v3);
  }
  for (; e < end; e++){
    unsigned int v = xs2[(size_t)csr[e]*64 + c2];
    ax += lo16(v); ay += hi16(v);
  }
  float di = dinv[i];
  s2[(size_t)i*64 + c2] = pack2(di * ax, di * ay);
}

// ---------------- fused Gram partials -> reduce -> analytic BN coefficients ----------
// grid (XB, ngrp), all blocks co-resident (<=256 blocks of 4 waves).
__global__ __launch_bounds__(256) void k_gramfit(const unsigned short* __restrict__ in,
                                                 int rstride, int coff128,
                                                 float* __restrict__ Gpart, float* __restrict__ msum,
                                                 float* __restrict__ G,
                                                 const float* __restrict__ W,
                                                 const float* __restrict__ gamma, const float* __restrict__ beta,
                                                 float* __restrict__ scale, float* __restrict__ shiftF,
                                                 float invN, int N, int gmul, int mmul,
                                                 int* __restrict__ bars){
  __shared__ unsigned short st[128 * 40];
  __shared__ float colsum[128];
  __shared__ float wl[4][132], ml[4][132];

  int gy = blockIdx.y;
  const unsigned short* src = in + gy * coff128;
  float* Gp = Gpart + ((size_t)gy * XB + blockIdx.x) * 16384;
  float* ms = msum + gy * mmul;   // mmul==0 => shared slot for stage1 (single group)

  int t = threadIdx.x;
  int wv = t >> 6, lane = t & 63, l16 = lane & 15, quad = lane >> 4;
  if (t < 128) colsum[t] = 0.f;
  int sn = t & 31, scb = t >> 5;

  ffrag acc[2][8];
  #pragma unroll
  for (int a = 0; a < 2; a++)
    #pragma unroll
    for (int b = 0; b < 8; b++) acc[a][b] = (ffrag){0.f,0.f,0.f,0.f};
  float cs[16];
  #pragma unroll
  for (int j = 0; j < 16; j++) cs[j] = 0.f;

  for (int c0 = blockIdx.x * 32; c0 < N; c0 += gridDim.x * 32){
    __syncthreads();
    int n = c0 + sn;
    ushort4 u0, u1, u2, u3;
    if (n < N){
      const ushort4* p = (const ushort4*)(src + (size_t)n * rstride + scb * 16);
      u0 = p[0]; u1 = p[1]; u2 = p[2]; u3 = p[3];
    } else {
      u0 = u1 = u2 = u3 = (ushort4){0,0,0,0};
    }
    unsigned short vals[16] = {u0.x,u0.y,u0.z,u0.w, u1.x,u1.y,u1.z,u1.w,
                               u2.x,u2.y,u2.z,u2.w, u3.x,u3.y,u3.z,u3.w};
    #pragma unroll
    for (int j = 0; j < 16; j++){
      st[(scb * 16 + j) * 40 + sn] = vals[j];
      cs[j] += bf2f(vals[j]);
    }
    __syncthreads();
    #pragma unroll
    for (int ta = 0; ta < 2; ta++){
      int ra = wv * 2 + ta;
      bfrag af = *(const bfrag*)&st[(ra * 16 + l16) * 40 + quad * 8];
      #pragma unroll
      for (int tb = 0; tb < 8; tb++){
        bfrag bf = *(const bfrag*)&st[(tb * 16 + l16) * 40 + quad * 8];
        acc[ta][tb] = __builtin_amdgcn_mfma_f32_16x16x32_bf16(af, bf, acc[ta][tb], 0, 0, 0);
      }
    }
  }
  #pragma unroll
  for (int j = 0; j < 16; j++) atomicAdd(&colsum[scb * 16 + j], cs[j]);
  __syncthreads();
  if (t < 128) atomicAdd(&ms[t], colsum[t]);
  #pragma unroll
  for (int ta = 0; ta < 2; ta++){
    #pragma unroll
    for (int tb = 0; tb < 8; tb++){
      int row0 = wv * 32 + ta * 16 + quad * 4;
      int colg = tb * 16 + l16;
      #pragma unroll
      for (int r = 0; r < 4; r++)
        Gp[(size_t)(row0 + r) * 128 + colg] = acc[ta][tb][r];
    }
  }

  int nblk = gridDim.x * gridDim.y;
  gbar(&bars[0], nblk);

  // stage B: reduce partials -> G (one element per thread)
  int gid = (blockIdx.y * gridDim.x + blockIdx.x) * 256 + t;
  int total = gridDim.y * 16384;
  for (int i = gid; i < total; i += nblk * 256){
    int grp = i >> 14, e = i & 16383;
    const float* srcp = Gpart + (size_t)grp * XB * 16384 + e;
    float s = 0.f;
    #pragma unroll 8
    for (int xb = 0; xb < XB; xb++) s += srcp[(size_t)xb * 16384];
    G[i] = s;
  }
  gbar(&bars[1], nblk);

  // stage C: per-column analytic BN (one column per wave per iter)
  int bidl = blockIdx.y * gridDim.x + blockIdx.x;
  for (int c = bidl * 4 + wv; c < 512; c += nblk * 4){
    int g = c >> 7, j = c & 127;
    const float* Wc = W + (size_t)g * 16384 + j;
    const float* Gg = G + (size_t)g * gmul;
    const float* mv = msum + g * mmul;
    for (int k = lane; k < 128; k += 64){ wl[wv][k] = Wc[(size_t)k * 128]; ml[wv][k] = mv[k] * invN; }
    float quadv = 0.f, dm = 0.f;
    #pragma unroll
    for (int kk = 0; kk < 2; kk++){
      int k = lane + kk * 64;
      float wk = wl[wv][k];
      dm += ml[wv][k] * wk;
      const float* Gr = Gg + (size_t)k * 128;
      float p = 0.f;
      for (int jj = 0; jj < 128; jj += 4){
        float4 gg = *(const float4*)(Gr + jj);
        float4 ww = *(const float4*)(&wl[wv][jj]);
        p += gg.x*ww.x + gg.y*ww.y + gg.z*ww.z + gg.w*ww.w;
      }
      quadv += wk * p;
    }
    for (int o = 32; o > 0; o >>= 1){
      quadv += __shfl_down(quadv, o);
      dm    += __shfl_down(dm, o);
    }
    if (lane == 0){
      float var = quadv * invN - dm * dm;
      float sc = gamma[c] * rsqrtf(var + EPS);
      scale[c] = sc;
      shiftF[c] = beta[c] - dm * sc;
    }
  }
}

// ---------------- mm1 fused: h = dinv * prelu(BN(s @ W1)), 32 nodes/block ----------
__global__ __launch_bounds__(256) void k_mm1f(const unsigned short* __restrict__ in,
                                              const unsigned short* __restrict__ Wt,
                                              const float* __restrict__ scale, const float* __restrict__ shiftF,
                                              const float* __restrict__ alpha_p, const float* __restrict__ dinv,
                                              unsigned short* __restrict__ h, int N){
  float alpha = alpha_p[0];
  int wave = threadIdx.x >> 6, lane = threadIdx.x & 63;
  int l16 = lane & 15, quad = lane >> 4;
  int node0 = blockIdx.x * 32 + l16;
  int node1 = node0 + 16;
  int nc0 = node0 < N ? node0 : N - 1;
  int nc1 = node1 < N ? node1 : N - 1;
  int colbase0 = wave * 128;
  float di0 = dinv[nc0], di1 = dinv[nc1];

  const unsigned short* ir0 = in + (size_t)nc0 * 128 + quad * 8;
  const unsigned short* ir1 = in + (size_t)nc1 * 128 + quad * 8;
  bfrag b0a = *(const bfrag*)(ir0),      b0b = *(const bfrag*)(ir1);
  bfrag b1a = *(const bfrag*)(ir0 + 32), b1b = *(const bfrag*)(ir1 + 32);
  bfrag b2a = *(const bfrag*)(ir0 + 64), b2b = *(const bfrag*)(ir1 + 64);
  bfrag b3a = *(const bfrag*)(ir0 + 96), b3b = *(const bfrag*)(ir1 + 96);

  #pragma unroll
  for (int ct = 0; ct < 8; ct++){
    int colbase = colbase0 + ct * 16;
    const unsigned short* wrow = Wt + (size_t)(colbase + l16) * 128 + quad * 8;
    bfrag a0 = *(const bfrag*)(wrow);
    bfrag a1 = *(const bfrag*)(wrow + 32);
    bfrag a2 = *(const bfrag*)(wrow + 64);
    bfrag a3 = *(const bfrag*)(wrow + 96);
    ffrag acc0 = {0.f,0.f,0.f,0.f}, acc1 = {0.f,0.f,0.f,0.f};
    acc0 = __builtin_amdgcn_mfma_f32_16x16x32_bf16(a0, b0a, acc0, 0, 0, 0);
    acc1 = __builtin_amdgcn_mfma_f32_16x16x32_bf16(a0, b0b, acc1, 0, 0, 0);
    acc0 = __builtin_amdgcn_mfma_f32_16x16x32_bf16(a1, b1a, acc0, 0, 0, 0);
    acc1 = __builtin_amdgcn_mfma_f32_16x16x32_bf16(a1, b1b, acc1, 0, 0, 0);
    acc0 = __builtin_amdgcn_mfma_f32_16x16x32_bf16(a2, b2a, acc0, 0, 0, 0);
    acc1 = __builtin_amdgcn_mfma_f32_16x16x32_bf16(a2, b2b, acc1, 0, 0, 0);
    acc0 = __builtin_amdgcn_mfma_f32_16x16x32_bf16(a3, b3a, acc0, 0, 0, 0);
    acc1 = __builtin_amdgcn_mfma_f32_16x16x32_bf16(a3, b3b, acc1, 0, 0, 0);
    int cb = colbase + quad * 4;
    float4 sc = *(const float4*)(scale + cb);
    float4 sh = *(const float4*)(shiftF + cb);
    float v0 = acc0[0]*sc.x + sh.x; v0 = v0 > 0.f ? v0 : alpha*v0;
    float v1 = acc0[1]*sc.y + sh.y; v1 = v1 > 0.f ? v1 : alpha*v1;
    float v2 = acc0[2]*sc.z + sh.z; v2 = v2 > 0.f ? v2 : alpha*v2;
    float v3 = acc0[3]*sc.w + sh.w; v3 = v3 > 0.f ? v3 : alpha*v3;
    float w0 = acc1[0]*sc.x + sh.x; w0 = w0 > 0.f ? w0 : alpha*w0;
    float w1 = acc1[1]*sc.y + sh.y; w1 = w1 > 0.f ? w1 : alpha*w1;
    float w2 = acc1[2]*sc.z + sh.z; w2 = w2 > 0.f ? w2 : alpha*w2;
    float w3 = acc1[3]*sc.w + sh.w; w3 = w3 > 0.f ? w3 : alpha*w3;
    uint2 o0, o1;
    o0.x = pack2(di0*v0, di0*v1); o0.y = pack2(di0*v2, di0*v3);
    o1.x = pack2(di1*w0, di1*w1); o1.y = pack2(di1*w2, di1*w3);
    if (node0 < N) *(uint2*)(h + (size_t)node0 * 512 + cb) = o0;
    if (node1 < N) *(uint2*)(h + (size_t)node1 * 512 + cb) = o1;
  }
}

// ---------------- t = P h : XCD-sliced, 1 node/wave, 16-wide unroll ----------------
__global__ __launch_bounds__(256) void k_prop_h(const unsigned int* __restrict__ h2,
                                                const int* __restrict__ csr,
                                                const int* __restrict__ offs, const int* __restrict__ indeg,
                                                const float* __restrict__ dinv,
                                                unsigned int* __restrict__ t2, int N){
  int B = blockIdx.x;
  int s = B & 3;
  int i = (B >> 2) * 4 + (threadIdx.x >> 6);
  if (i >= N) return;
  int c2 = s * 64 + (threadIdx.x & 63);
  unsigned int sv = h2[(size_t)i*256 + c2];
  float ax = lo16(sv), ay = hi16(sv);
  int e = offs[i], end = e + indeg[i];
  for (; e + 16 <= end; e += 16){
    int r[16];
    #pragma unroll
    for (int j = 0; j < 16; j++) r[j] = csr[e + j];
    unsigned int v[16];
    #pragma unroll
    for (int j = 0; j < 16; j++) v[j] = h2[(size_t)r[j]*256 + c2];
    #pragma unroll
    for (int j = 0; j < 16; j++){ ax += lo16(v[j]); ay += hi16(v[j]); }
  }
  for (; e + 4 <= end; e += 4){
    int r0 = csr[e], r1 = csr[e+1], r2 = csr[e+2], r3 = csr[e+3];
    unsigned int v0 = h2[(size_t)r0*256 + c2], v1 = h2[(size_t)r1*256 + c2];
    unsigned int v2 = h2[(size_t)r2*256 + c2], v3 = h2[(size_t)r3*256 + c2];
    ax += lo16(v0)+lo16(v1)+lo16(v2)+lo16(v3);
    ay += hi16(v0)+hi16(v1)+hi16(v2)+hi16(v3);
  }
  for (; e < end; e++){
    unsigned int v = h2[(size_t)csr[e]*256 + c2];
    ax += lo16(v); ay += hi16(v);
  }
  float di = dinv[i];
  t2[(size_t)i*256 + c2] = pack2(di * ax, di * ay);
}

// ---------------- mm2 fused: out = sum_g mix_g * prelu(BN(t_g @ W2_g)) ----------
__global__ __launch_bounds__(256) void k_mm2f(const unsigned short* __restrict__ t,
                                              const unsigned short* __restrict__ Wt,
                                              const float* __restrict__ scale, const float* __restrict__ shiftF,
                                              const float* __restrict__ alpha_p, const float* __restrict__ mixe,
                                              float* __restrict__ out, int N){
  __shared__ float red[4][16][132];
  float alpha = alpha_p[0];
  int wave = threadIdx.x >> 6, lane = threadIdx.x & 63;
  int l16 = lane & 15, quad = lane >> 4;
  int node = blockIdx.x * 16 + l16;
  int nc = node < N ? node : N - 1;

  float4 me = ((const float4*)mixe)[nc];
  float mx = fmaxf(fmaxf(me.x, me.y), fmaxf(me.z, me.w));
  float e0 = __expf(me.x - mx), e1 = __expf(me.y - mx), e2 = __expf(me.z - mx), e3 = __expf(me.w - mx);
  float inv = 1.f / (e0 + e1 + e2 + e3);
  float wvx = ((wave == 0) ? e0 : (wave == 1) ? e1 : (wave == 2) ? e2 : e3) * inv;

  const unsigned short* inrow = t + (size_t)nc * 512 + wave * 128 + quad * 8;
  bfrag b0 = *(const bfrag*)(inrow);
  bfrag b1 = *(const bfrag*)(inrow + 32);
  bfrag b2 = *(const bfrag*)(inrow + 64);
  bfrag b3 = *(const bfrag*)(inrow + 96);

  #pragma unroll
  for (int ct = 0; ct < 8; ct++){
    int c512 = wave * 128 + ct * 16;
    const unsigned short* wrow = Wt + (size_t)(c512 + l16) * 128 + quad * 8;
    bfrag a0 = *(const bfrag*)(wrow);
    bfrag a1 = *(const bfrag*)(wrow + 32);
    bfrag a2 = *(const bfrag*)(wrow + 64);
    bfrag a3 = *(const bfrag*)(wrow + 96);
    ffrag acc = {0.f, 0.f, 0.f, 0.f};
    acc = __builtin_amdgcn_mfma_f32_16x16x32_bf16(a0, b0, acc, 0, 0, 0);
    acc = __builtin_amdgcn_mfma_f32_16x16x32_bf16(a1, b1, acc, 0, 0, 0);
    acc = __builtin_amdgcn_mfma_f32_16x16x32_bf16(a2, b2, acc, 0, 0, 0);
    acc = __builtin_amdgcn_mfma_f32_16x16x32_bf16(a3, b3, acc, 0, 0, 0);
    int cb = c512 + quad * 4;
    float4 sc = *(const float4*)(scale + cb);
    float4 sh = *(const float4*)(shiftF + cb);
    float v0 = acc[0]*sc.x + sh.x; v0 = v0 > 0.f ? v0 : alpha*v0;
    float v1 = acc[1]*sc.y + sh.y; v1 = v1 > 0.f ? v1 : alpha*v1;
    float v2 = acc[2]*sc.z + sh.z; v2 = v2 > 0.f ? v2 : alpha*v2;
    float v3 = acc[3]*sc.w + sh.w; v3 = v3 > 0.f ? v3 : alpha*v3;
    int j = ct * 16 + quad * 4;
    float4 wr = {wvx*v0, wvx*v1, wvx*v2, wvx*v3};
    *(float4*)&red[wave][l16][j] = wr;
  }
  __syncthreads();
  int tt = threadIdx.x;
  int nn = tt >> 4, j0 = (tt & 15) * 8;
  int gnode = blockIdx.x * 16 + nn;
  if (gnode < N){
    float4 r0 = {0,0,0,0}, r1 = {0,0,0,0};
    #pragma unroll
    for (int w = 0; w < 4; w++){
      float4 p0 = *(const float4*)&red[w][nn][j0];
      float4 p1 = *(const float4*)&red[w][nn][j0 + 4];
      r0.x += p0.x; r0.y += p0.y; r0.z += p0.z; r0.w += p0.w;
      r1.x += p1.x; r1.y += p1.y; r1.z += p1.z; r1.w += p1.w;
    }
    float* op = out + (size_t)gnode * 128 + j0;
    *(float4*)(op) = r0;
    *(float4*)(op + 4) = r1;
  }
}

extern "C" void kernel_launch(void* const* d_in, const int* in_sizes, int n_in,
                              void* d_out, int out_size, void* d_ws, size_t ws_size,
                              hipStream_t stream) {
  const float* x      = (const float*)d_in[0];
  const int*   ei     = (const int*)d_in[1];
  const float* W1     = (const float*)d_in[2];
  const float* W2     = (const float*)d_in[4];
  const float* gamma1 = (const float*)d_in[6];
  const float* beta1  = (const float*)d_in[7];
  const float* gamma2 = (const float*)d_in[8];
  const float* beta2  = (const float*)d_in[9];
  const float* alpha  = (const float*)d_in[10];
  const float* mixe   = (const float*)d_in[11];
  float* out = (float*)d_out;

  const int N = in_sizes[0] / 128;
  const int E = in_sizes[1] / 2;
  const int* rowv = ei;
  const int* colv = ei + E;

  char* w = (char*)d_ws;
  size_t off = 0;
  auto take = [&](size_t bytes) -> void* {
    void* p = w + off;
    off = (off + bytes + 255) & ~(size_t)255;
    return p;
  };
  // --- zeroed region (single memset): indeg | ctr | bars | m1 | m2 ---
  size_t zbeg = off;
  int*   indeg  = (int*)take((size_t)N * 4);
  int*   ctr    = (int*)take(256);
  int*   bars   = (int*)take(256);   // barrier slots: graph 0-1, gramfit1 4-5, gramfit2 8-9
  float* m1     = (float*)take(512);
  float* m2     = (float*)take(2048);
  size_t zend = off;
  // --- rest (no init needed) ---
  float* G1     = (float*)take(65536);
  float* G2     = (float*)take(262144);
  float* Gpart  = (float*)take((size_t)4 * XB * 16384 * 4);
  int*   cursor = (int*)take((size_t)N * 4);
  int*   offs   = (int*)take((size_t)N * 4);
  float* dinv   = (float*)take((size_t)N * 4);
  float* scale1 = (float*)take(2048);
  float* shift1 = (float*)take(2048);
  float* scale2 = (float*)take(2048);
  float* shift2 = (float*)take(2048);
  int*   csr    = (int*)take((size_t)E * 4);
  unsigned short* Wt1 = (unsigned short*)take(512 * 128 * 2);
  unsigned short* Wt2 = (unsigned short*)take(512 * 128 * 2);
  unsigned short* xs = (unsigned short*)take((size_t)N * 128 * 2);
  unsigned short* sb = (unsigned short*)take((size_t)N * 128 * 2);
  unsigned short* h  = (unsigned short*)take((size_t)N * 512 * 2);
  unsigned short* tb = (unsigned short*)take((size_t)N * 512 * 2);

  hipMemsetAsync((char*)d_ws + zbeg, 0, zend - zbeg, stream);

  float invN = 1.0f / (float)N;

  // graph build: deg+wcast | alloc | scatter+castx (one kernel, 2 grid barriers)
  k_graph<<<512, 256, 0, stream>>>(rowv, colv, N, E, indeg, ctr, offs, cursor, dinv, csr,
                                   x, xs, W1, W2, Wt1, Wt2, bars);

  k_prop_x<<<(N + 3) / 4, 256, 0, stream>>>((const unsigned int*)xs, csr, offs, indeg, dinv, (unsigned int*)sb, N);

  // stage 1: fused Gram->reduce->BN-fit, then fused GEMM epilogue -> h
  k_gramfit<<<dim3(XB, 1), 256, 0, stream>>>(sb, 128, 0, Gpart, m1, G1,
                                             W1, gamma1, beta1, scale1, shift1, invN, N, 0, 0, bars + 4);
  k_mm1f<<<(N + 31) / 32, 256, 0, stream>>>(sb, Wt1, scale1, shift1, alpha, dinv, h, N);

  k_prop_h<<<((N + 3) / 4) * 4, 256, 0, stream>>>((const unsigned int*)h, csr, offs, indeg, dinv, (unsigned int*)tb, N);

  // stage 2: fused per-group Gram->reduce->BN-fit, then fused GEMM->mix->sum -> out
  k_gramfit<<<dim3(XB, 4), 256, 0, stream>>>(tb, 512, 128, Gpart, m2, G2,
                                             W2, gamma2, beta2, scale2, shift2, invN, N, 16384, 128, bars + 8);
  k_mm2f<<<(N + 15) / 16, 256, 0, stream>>>(tb, Wt2, scale2, shift2, alpha, mixe, out, N);
}

// Round 9
// 552.717 us; speedup vs baseline: 1.4177x; 1.4177x over previous
//
#include <hip/hip_runtime.h>
#include <stdint.h>

static constexpr float EPS = 1e-5f;
static constexpr int XB = 64;   // gram split-K partial blocks

typedef __attribute__((ext_vector_type(8))) short bfrag;
typedef __attribute__((ext_vector_type(4))) float ffrag;

__device__ __forceinline__ float bf2f(unsigned short u){
  union { unsigned int i; float f; } v; v.i = ((unsigned int)u) << 16; return v.f;
}
__device__ __forceinline__ unsigned short f2bf(float f){
  union { float f; unsigned int i; } v; v.f = f;
  unsigned int x = v.i;
  x += 0x7fffu + ((x >> 16) & 1u);   // round-to-nearest-even
  return (unsigned short)(x >> 16);
}
__device__ __forceinline__ float lo16(unsigned int v){ return bf2f((unsigned short)(v & 0xffffu)); }
__device__ __forceinline__ float hi16(unsigned int v){ return bf2f((unsigned short)(v >> 16)); }
__device__ __forceinline__ unsigned int pack2(float a, float b){
  return ((unsigned int)f2bf(b) << 16) | (unsigned int)f2bf(a);
}

// ---------------- deg (2 edges/thread) + fused W transpose/cast ----------------
__global__ __launch_bounds__(256) void k_deg(const int* __restrict__ col, int* __restrict__ indeg,
                                             int N, int E, int dbl,
                                             const float* __restrict__ W1, const float* __restrict__ W2,
                                             unsigned short* __restrict__ Wt1, unsigned short* __restrict__ Wt2){
  int b = blockIdx.x;
  if (b < dbl){
    int e0 = (b * 256 + threadIdx.x) * 2;
    if (e0 < E){
      if (e0 + 1 < E){
        int2 cc = *(const int2*)&col[e0];
        unsigned c0 = (unsigned)cc.x, c1 = (unsigned)cc.y;
        if (c0 < (unsigned)N) atomicAdd(&indeg[c0], 1);
        if (c1 < (unsigned)N) atomicAdd(&indeg[c1], 1);
      } else {
        unsigned c0 = (unsigned)col[e0];
        if (c0 < (unsigned)N) atomicAdd(&indeg[c0], 1);
      }
    }
  } else {
    int idx = (b - dbl) * 256 + threadIdx.x;   // [0, 131072)
    const float* W = W1; unsigned short* Wt = Wt1;
    if (idx >= 65536){ idx -= 65536; W = W2; Wt = Wt2; }
    int c = idx >> 7, k = idx & 127;
    int g = c >> 7, j = c & 127;
    Wt[(size_t)c * 128 + k] = f2bf(W[(size_t)g*16384 + k*128 + j]);
  }
}

// wave-scan allocation: offs[i] = nondeterministic but valid disjoint CSR ranges.
__global__ void k_alloc(const int* __restrict__ indeg, int* __restrict__ ctr,
                        int* __restrict__ offs, int* __restrict__ cursor,
                        float* __restrict__ dinv, int N){
  int tid = blockIdx.x * 256 + threadIdx.x;
  int lane = threadIdx.x & 63;
  int v = (tid < N) ? indeg[tid] : 0;
  int incl = v;
  #pragma unroll
  for (int d = 1; d < 64; d <<= 1){
    int u = __shfl_up(incl, d);
    if (lane >= d) incl += u;
  }
  int base = 0;
  if (lane == 63) base = atomicAdd(ctr, incl);
  base = __shfl(base, 63);
  if (tid < N){
    int o = base + incl - v;
    offs[tid] = o; cursor[tid] = o;
    dinv[tid] = rsqrtf((float)(v + 1));
  }
}

// ---------------- scatter (2 edges/thread) + fused xs = bf16(dinv*x) ----------------
__global__ __launch_bounds__(256) void k_scatter(const int* __restrict__ row, const int* __restrict__ col,
                                                 int* __restrict__ cursor, int* __restrict__ csr,
                                                 int N, int E, int sbl,
                                                 const float* __restrict__ x, const float* __restrict__ dinv,
                                                 unsigned short* __restrict__ xs, int total4x){
  int b = blockIdx.x;
  if (b < sbl){
    int e0 = (b * 256 + threadIdx.x) * 2;
    #pragma unroll
    for (int q = 0; q < 2; q++){
      int e = e0 + q;
      if (e < E){
        unsigned c = (unsigned)col[e];
        if (c < (unsigned)N){
          int p = atomicAdd(&cursor[c], 1);
          unsigned r = (unsigned)row[e];
          csr[p] = (r < (unsigned)N) ? (int)r : 0;
        }
      }
    }
  } else {
    int idx = (b - sbl) * 256 + threadIdx.x;
    int stride = (gridDim.x - sbl) * 256;
    for (; idx < total4x; idx += stride){
      int i = idx >> 5;
      float di = dinv[i];
      float4 v = ((const float4*)x)[idx];
      ushort4 o;
      o.x = f2bf(di * v.x); o.y = f2bf(di * v.y);
      o.z = f2bf(di * v.z); o.w = f2bf(di * v.w);
      ((ushort4*)xs)[idx] = o;
    }
  }
}

// ---------------- s = P x : 1 node/wave, 16-wide unroll ----------------
__global__ __launch_bounds__(256) void k_prop_x(const unsigned int* __restrict__ xs2,
                                               const int* __restrict__ csr,
                                               const int* __restrict__ offs, const int* __restrict__ indeg,
                                               const float* __restrict__ dinv,
                                               unsigned int* __restrict__ s2, int N){
  int i = blockIdx.x * 4 + (threadIdx.x >> 6);
  if (i >= N) return;
  int c2 = threadIdx.x & 63;
  unsigned int sv = xs2[(size_t)i*64 + c2];
  float ax = lo16(sv), ay = hi16(sv);
  int e = offs[i], end = e + indeg[i];
  for (; e + 16 <= end; e += 16){
    int r[16];
    #pragma unroll
    for (int j = 0; j < 16; j++) r[j] = csr[e + j];
    unsigned int v[16];
    #pragma unroll
    for (int j = 0; j < 16; j++) v[j] = xs2[(size_t)r[j]*64 + c2];
    #pragma unroll
    for (int j = 0; j < 16; j++){ ax += lo16(v[j]); ay += hi16(v[j]); }
  }
  for (; e + 4 <= end; e += 4){
    int r0 = csr[e], r1 = csr[e+1], r2 = csr[e+2], r3 = csr[e+3];
    unsigned int v0 = xs2[(size_t)r0*64 + c2], v1 = xs2[(size_t)r1*64 + c2];
    unsigned int v2 = xs2[(size_t)r2*64 + c2], v3 = xs2[(size_t)r3*64 + c2];
    ax += lo16(v0)+lo16(v1)+lo16(v2)+lo16(v3);
    ay += hi16(v0)+hi16(v1)+hi16(v2)+hi16(v3);
  }
  for (; e < end; e++){
    unsigned int v = xs2[(size_t)csr[e]*64 + c2];
    ax += lo16(v); ay += hi16(v);
  }
  float di = dinv[i];
  s2[(size_t)i*64 + c2] = pack2(di * ax, di * ay);
}

// ---------------- Gram partials + column sums over a 128-col slice (MFMA) ----------------
__global__ __launch_bounds__(256) void k_gram(const unsigned short* __restrict__ in,
                                              int rstride, int coff128,
                                              float* __restrict__ Gpart, float* __restrict__ msumbase,
                                              int N){
  int gy = blockIdx.y;
  const unsigned short* src = in + gy * coff128;
  float* Gp = Gpart + ((size_t)gy * XB + blockIdx.x) * 16384;
  float* msum = msumbase + gy * 128;

  __shared__ unsigned short st[128 * 40];
  __shared__ float colsum[128];

  int t = threadIdx.x;
  int wv = t >> 6, lane = t & 63, l16 = lane & 15, quad = lane >> 4;
  if (t < 128) colsum[t] = 0.f;

  int sn = t & 31, scb = t >> 5;

  ffrag acc[2][8];
  #pragma unroll
  for (int a = 0; a < 2; a++)
    #pragma unroll
    for (int b = 0; b < 8; b++) acc[a][b] = (ffrag){0.f,0.f,0.f,0.f};

  float cs[16];
  #pragma unroll
  for (int j = 0; j < 16; j++) cs[j] = 0.f;

  for (int c0 = blockIdx.x * 32; c0 < N; c0 += gridDim.x * 32){
    __syncthreads();
    int n = c0 + sn;
    ushort4 u0, u1, u2, u3;
    if (n < N){
      const ushort4* p = (const ushort4*)(src + (size_t)n * rstride + scb * 16);
      u0 = p[0]; u1 = p[1]; u2 = p[2]; u3 = p[3];
    } else {
      u0 = u1 = u2 = u3 = (ushort4){0,0,0,0};
    }
    unsigned short vals[16] = {u0.x,u0.y,u0.z,u0.w, u1.x,u1.y,u1.z,u1.w,
                               u2.x,u2.y,u2.z,u2.w, u3.x,u3.y,u3.z,u3.w};
    #pragma unroll
    for (int j = 0; j < 16; j++){
      st[(scb * 16 + j) * 40 + sn] = vals[j];
      cs[j] += bf2f(vals[j]);
    }
    __syncthreads();
    #pragma unroll
    for (int ta = 0; ta < 2; ta++){
      int ra = wv * 2 + ta;
      bfrag af = *(const bfrag*)&st[(ra * 16 + l16) * 40 + quad * 8];
      #pragma unroll
      for (int tb = 0; tb < 8; tb++){
        bfrag bf = *(const bfrag*)&st[(tb * 16 + l16) * 40 + quad * 8];
        acc[ta][tb] = __builtin_amdgcn_mfma_f32_16x16x32_bf16(af, bf, acc[ta][tb], 0, 0, 0);
      }
    }
  }
  #pragma unroll
  for (int j = 0; j < 16; j++) atomicAdd(&colsum[scb * 16 + j], cs[j]);
  __syncthreads();
  if (t < 128) atomicAdd(&msum[t], colsum[t]);
  #pragma unroll
  for (int ta = 0; ta < 2; ta++){
    #pragma unroll
    for (int tb = 0; tb < 8; tb++){
      int row0 = wv * 32 + ta * 16 + quad * 4;
      int colg = tb * 16 + l16;
      #pragma unroll
      for (int r = 0; r < 4; r++)
        Gp[(size_t)(row0 + r) * 128 + colg] = acc[ta][tb][r];
    }
  }
}

// ---------------- reduce gram partials ----------------
__global__ __launch_bounds__(256) void k_gred(const float* __restrict__ Gpart, float* __restrict__ G){
  int i = blockIdx.x * 256 + threadIdx.x;        // [0, 16384)
  int grp = blockIdx.y;
  const float* src = Gpart + (size_t)grp * XB * 16384;
  float s = 0.f;
  #pragma unroll 4
  for (int xb = 0; xb < XB; xb++) s += src[(size_t)xb * 16384 + i];
  G[(size_t)grp * 16384 + i] = s;
}

// ---------------- analytic BN coefficients from Gram ----------------
__global__ __launch_bounds__(64) void k_bnfit(const float* __restrict__ W,
                                              const float* __restrict__ gamma, const float* __restrict__ beta,
                                              const float* __restrict__ Gbase, int gmul,
                                              const float* __restrict__ msumbase, int mmul,
                                              float* __restrict__ scale, float* __restrict__ shiftF,
                                              float invN){
  int c = blockIdx.x;
  int g = c >> 7, j = c & 127;
  const float* Wc = W + (size_t)g * 16384 + j;
  const float* G  = Gbase + (size_t)g * gmul;
  const float* mv = msumbase + g * mmul;
  __shared__ float wl[128];
  __shared__ float ml[128];
  int t = threadIdx.x;
  for (int k = t; k < 128; k += 64){ wl[k] = Wc[(size_t)k * 128]; ml[k] = mv[k] * invN; }
  __syncthreads();
  float quad = 0.f, dm = 0.f;
  #pragma unroll
  for (int kk = 0; kk < 2; kk++){
    int k = t + kk * 64;
    float wk = wl[k];
    dm += ml[k] * wk;
    const float* Gr = G + (size_t)k * 128;
    float p = 0.f;
    for (int jj = 0; jj < 128; jj += 4){
      float4 gg = *(const float4*)(Gr + jj);
      float4 ww = *(const float4*)(wl + jj);
      p += gg.x*ww.x + gg.y*ww.y + gg.z*ww.z + gg.w*ww.w;
    }
    quad += wk * p;
  }
  for (int o = 32; o > 0; o >>= 1){
    quad += __shfl_down(quad, o);
    dm   += __shfl_down(dm, o);
  }
  if (t == 0){
    float var = quad * invN - dm * dm;
    float sc = gamma[c] * rsqrtf(var + EPS);
    scale[c] = sc;
    shiftF[c] = beta[c] - dm * sc;
  }
}

// ---------------- mm1 fused: h = dinv * prelu(BN(s @ W1)), 32 nodes/block ----------
__global__ __launch_bounds__(256) void k_mm1f(const unsigned short* __restrict__ in,
                                              const unsigned short* __restrict__ Wt,
                                              const float* __restrict__ scale, const float* __restrict__ shiftF,
                                              const float* __restrict__ alpha_p, const float* __restrict__ dinv,
                                              unsigned short* __restrict__ h, int N){
  float alpha = alpha_p[0];
  int wave = threadIdx.x >> 6, lane = threadIdx.x & 63;
  int l16 = lane & 15, quad = lane >> 4;
  int node0 = blockIdx.x * 32 + l16;
  int node1 = node0 + 16;
  int nc0 = node0 < N ? node0 : N - 1;
  int nc1 = node1 < N ? node1 : N - 1;
  int colbase0 = wave * 128;
  float di0 = dinv[nc0], di1 = dinv[nc1];

  const unsigned short* ir0 = in + (size_t)nc0 * 128 + quad * 8;
  const unsigned short* ir1 = in + (size_t)nc1 * 128 + quad * 8;
  bfrag b0a = *(const bfrag*)(ir0),      b0b = *(const bfrag*)(ir1);
  bfrag b1a = *(const bfrag*)(ir0 + 32), b1b = *(const bfrag*)(ir1 + 32);
  bfrag b2a = *(const bfrag*)(ir0 + 64), b2b = *(const bfrag*)(ir1 + 64);
  bfrag b3a = *(const bfrag*)(ir0 + 96), b3b = *(const bfrag*)(ir1 + 96);

  #pragma unroll
  for (int ct = 0; ct < 8; ct++){
    int colbase = colbase0 + ct * 16;
    const unsigned short* wrow = Wt + (size_t)(colbase + l16) * 128 + quad * 8;
    bfrag a0 = *(const bfrag*)(wrow);
    bfrag a1 = *(const bfrag*)(wrow + 32);
    bfrag a2 = *(const bfrag*)(wrow + 64);
    bfrag a3 = *(const bfrag*)(wrow + 96);
    ffrag acc0 = {0.f,0.f,0.f,0.f}, acc1 = {0.f,0.f,0.f,0.f};
    acc0 = __builtin_amdgcn_mfma_f32_16x16x32_bf16(a0, b0a, acc0, 0, 0, 0);
    acc1 = __builtin_amdgcn_mfma_f32_16x16x32_bf16(a0, b0b, acc1, 0, 0, 0);
    acc0 = __builtin_amdgcn_mfma_f32_16x16x32_bf16(a1, b1a, acc0, 0, 0, 0);
    acc1 = __builtin_amdgcn_mfma_f32_16x16x32_bf16(a1, b1b, acc1, 0, 0, 0);
    acc0 = __builtin_amdgcn_mfma_f32_16x16x32_bf16(a2, b2a, acc0, 0, 0, 0);
    acc1 = __builtin_amdgcn_mfma_f32_16x16x32_bf16(a2, b2b, acc1, 0, 0, 0);
    acc0 = __builtin_amdgcn_mfma_f32_16x16x32_bf16(a3, b3a, acc0, 0, 0, 0);
    acc1 = __builtin_amdgcn_mfma_f32_16x16x32_bf16(a3, b3b, acc1, 0, 0, 0);
    int cb = colbase + quad * 4;
    float4 sc = *(const float4*)(scale + cb);
    float4 sh = *(const float4*)(shiftF + cb);
    float v0 = acc0[0]*sc.x + sh.x; v0 = v0 > 0.f ? v0 : alpha*v0;
    float v1 = acc0[1]*sc.y + sh.y; v1 = v1 > 0.f ? v1 : alpha*v1;
    float v2 = acc0[2]*sc.z + sh.z; v2 = v2 > 0.f ? v2 : alpha*v2;
    float v3 = acc0[3]*sc.w + sh.w; v3 = v3 > 0.f ? v3 : alpha*v3;
    float w0 = acc1[0]*sc.x + sh.x; w0 = w0 > 0.f ? w0 : alpha*w0;
    float w1 = acc1[1]*sc.y + sh.y; w1 = w1 > 0.f ? w1 : alpha*w1;
    float w2 = acc1[2]*sc.z + sh.z; w2 = w2 > 0.f ? w2 : alpha*w2;
    float w3 = acc1[3]*sc.w + sh.w; w3 = w3 > 0.f ? w3 : alpha*w3;
    uint2 o0, o1;
    o0.x = pack2(di0*v0, di0*v1); o0.y = pack2(di0*v2, di0*v3);
    o1.x = pack2(di1*w0, di1*w1); o1.y = pack2(di1*w2, di1*w3);
    if (node0 < N) *(uint2*)(h + (size_t)node0 * 512 + cb) = o0;
    if (node1 < N) *(uint2*)(h + (size_t)node1 * 512 + cb) = o1;
  }
}

// ---------------- t = P h : half-column launch (coff = u32 col offset) ----------------
// 2 nodes/block, 128 thr/node (both waves of a node run identical edge loops).
__global__ __launch_bounds__(256) void k_prop_h(const unsigned int* __restrict__ h2,
                                                const int* __restrict__ csr,
                                                const int* __restrict__ offs, const int* __restrict__ indeg,
                                                const float* __restrict__ dinv,
                                                unsigned int* __restrict__ t2, int N, int coff){
  int i = blockIdx.x * 2 + (threadIdx.x >> 7);
  if (i >= N) return;
  int c2 = coff + (threadIdx.x & 127);
  unsigned int sv = h2[(size_t)i*256 + c2];
  float ax = lo16(sv), ay = hi16(sv);
  int e = offs[i], end = e + indeg[i];
  for (; e + 16 <= end; e += 16){
    int r[16];
    #pragma unroll
    for (int j = 0; j < 16; j++) r[j] = csr[e + j];
    unsigned int v[16];
    #pragma unroll
    for (int j = 0; j < 16; j++) v[j] = h2[(size_t)r[j]*256 + c2];
    #pragma unroll
    for (int j = 0; j < 16; j++){ ax += lo16(v[j]); ay += hi16(v[j]); }
  }
  for (; e + 4 <= end; e += 4){
    int r0 = csr[e], r1 = csr[e+1], r2 = csr[e+2], r3 = csr[e+3];
    unsigned int v0 = h2[(size_t)r0*256 + c2], v1 = h2[(size_t)r1*256 + c2];
    unsigned int v2 = h2[(size_t)r2*256 + c2], v3 = h2[(size_t)r3*256 + c2];
    ax += lo16(v0)+lo16(v1)+lo16(v2)+lo16(v3);
    ay += hi16(v0)+hi16(v1)+hi16(v2)+hi16(v3);
  }
  for (; e < end; e++){
    unsigned int v = h2[(size_t)csr[e]*256 + c2];
    ax += lo16(v); ay += hi16(v);
  }
  float di = dinv[i];
  t2[(size_t)i*256 + c2] = pack2(di * ax, di * ay);
}

// ---------------- mm2 fused: out = sum_g mix_g * prelu(BN(t_g @ W2_g)) ----------
__global__ __launch_bounds__(256) void k_mm2f(const unsigned short* __restrict__ t,
                                              const unsigned short* __restrict__ Wt,
                                              const float* __restrict__ scale, const float* __restrict__ shiftF,
                                              const float* __restrict__ alpha_p, const float* __restrict__ mixe,
                                              float* __restrict__ out, int N){
  __shared__ float red[4][16][132];
  float alpha = alpha_p[0];
  int wave = threadIdx.x >> 6, lane = threadIdx.x & 63;
  int l16 = lane & 15, quad = lane >> 4;
  int node = blockIdx.x * 16 + l16;
  int nc = node < N ? node : N - 1;

  float4 me = ((const float4*)mixe)[nc];
  float mx = fmaxf(fmaxf(me.x, me.y), fmaxf(me.z, me.w));
  float e0 = __expf(me.x - mx), e1 = __expf(me.y - mx), e2 = __expf(me.z - mx), e3 = __expf(me.w - mx);
  float inv = 1.f / (e0 + e1 + e2 + e3);
  float wvx = ((wave == 0) ? e0 : (wave == 1) ? e1 : (wave == 2) ? e2 : e3) * inv;

  const unsigned short* inrow = t + (size_t)nc * 512 + wave * 128 + quad * 8;
  bfrag b0 = *(const bfrag*)(inrow);
  bfrag b1 = *(const bfrag*)(inrow + 32);
  bfrag b2 = *(const bfrag*)(inrow + 64);
  bfrag b3 = *(const bfrag*)(inrow + 96);

  #pragma unroll
  for (int ct = 0; ct < 8; ct++){
    int c512 = wave * 128 + ct * 16;
    const unsigned short* wrow = Wt + (size_t)(c512 + l16) * 128 + quad * 8;
    bfrag a0 = *(const bfrag*)(wrow);
    bfrag a1 = *(const bfrag*)(wrow + 32);
    bfrag a2 = *(const bfrag*)(wrow + 64);
    bfrag a3 = *(const bfrag*)(wrow + 96);
    ffrag acc = {0.f, 0.f, 0.f, 0.f};
    acc = __builtin_amdgcn_mfma_f32_16x16x32_bf16(a0, b0, acc, 0, 0, 0);
    acc = __builtin_amdgcn_mfma_f32_16x16x32_bf16(a1, b1, acc, 0, 0, 0);
    acc = __builtin_amdgcn_mfma_f32_16x16x32_bf16(a2, b2, acc, 0, 0, 0);
    acc = __builtin_amdgcn_mfma_f32_16x16x32_bf16(a3, b3, acc, 0, 0, 0);
    int cb = c512 + quad * 4;
    float4 sc = *(const float4*)(scale + cb);
    float4 sh = *(const float4*)(shiftF + cb);
    float v0 = acc[0]*sc.x + sh.x; v0 = v0 > 0.f ? v0 : alpha*v0;
    float v1 = acc[1]*sc.y + sh.y; v1 = v1 > 0.f ? v1 : alpha*v1;
    float v2 = acc[2]*sc.z + sh.z; v2 = v2 > 0.f ? v2 : alpha*v2;
    float v3 = acc[3]*sc.w + sh.w; v3 = v3 > 0.f ? v3 : alpha*v3;
    int j = ct * 16 + quad * 4;
    float4 wr = {wvx*v0, wvx*v1, wvx*v2, wvx*v3};
    *(float4*)&red[wave][l16][j] = wr;
  }
  __syncthreads();
  int tt = threadIdx.x;
  int nn = tt >> 4, j0 = (tt & 15) * 8;
  int gnode = blockIdx.x * 16 + nn;
  if (gnode < N){
    float4 r0 = {0,0,0,0}, r1 = {0,0,0,0};
    #pragma unroll
    for (int w = 0; w < 4; w++){
      float4 p0 = *(const float4*)&red[w][nn][j0];
      float4 p1 = *(const float4*)&red[w][nn][j0 + 4];
      r0.x += p0.x; r0.y += p0.y; r0.z += p0.z; r0.w += p0.w;
      r1.x += p1.x; r1.y += p1.y; r1.z += p1.z; r1.w += p1.w;
    }
    float* op = out + (size_t)gnode * 128 + j0;
    *(float4*)(op) = r0;
    *(float4*)(op + 4) = r1;
  }
}

extern "C" void kernel_launch(void* const* d_in, const int* in_sizes, int n_in,
                              void* d_out, int out_size, void* d_ws, size_t ws_size,
                              hipStream_t stream) {
  const float* x      = (const float*)d_in[0];
  const int*   ei     = (const int*)d_in[1];
  const float* W1     = (const float*)d_in[2];
  const float* W2     = (const float*)d_in[4];
  const float* gamma1 = (const float*)d_in[6];
  const float* beta1  = (const float*)d_in[7];
  const float* gamma2 = (const float*)d_in[8];
  const float* beta2  = (const float*)d_in[9];
  const float* alpha  = (const float*)d_in[10];
  const float* mixe   = (const float*)d_in[11];
  float* out = (float*)d_out;

  const int N = in_sizes[0] / 128;
  const int E = in_sizes[1] / 2;
  const int* rowv = ei;
  const int* colv = ei + E;

  char* w = (char*)d_ws;
  size_t off = 0;
  auto take = [&](size_t bytes) -> void* {
    void* p = w + off;
    off = (off + bytes + 255) & ~(size_t)255;
    return p;
  };
  // --- zeroed region (single memset): indeg | ctr | m1 | m2 ---
  size_t zbeg = off;
  int*   indeg  = (int*)take((size_t)N * 4);
  int*   ctr    = (int*)take(256);
  float* m1     = (float*)take(512);
  float* m2     = (float*)take(2048);
  size_t zend = off;
  // --- rest (no init needed) ---
  float* G1     = (float*)take(65536);
  float* G2     = (float*)take(262144);
  float* Gpart  = (float*)take((size_t)4 * XB * 16384 * 4);
  int*   cursor = (int*)take((size_t)N * 4);
  int*   offs   = (int*)take((size_t)N * 4);
  float* dinv   = (float*)take((size_t)N * 4);
  float* scale1 = (float*)take(2048);
  float* shift1 = (float*)take(2048);
  float* scale2 = (float*)take(2048);
  float* shift2 = (float*)take(2048);
  int*   csr    = (int*)take((size_t)E * 4);
  unsigned short* Wt1 = (unsigned short*)take(512 * 128 * 2);
  unsigned short* Wt2 = (unsigned short*)take(512 * 128 * 2);
  unsigned short* xs = (unsigned short*)take((size_t)N * 128 * 2);
  unsigned short* sb = (unsigned short*)take((size_t)N * 128 * 2);
  unsigned short* h  = (unsigned short*)take((size_t)N * 512 * 2);
  unsigned short* tb = (unsigned short*)take((size_t)N * 512 * 2);

  hipMemsetAsync((char*)d_ws + zbeg, 0, zend - zbeg, stream);

  int nb  = (N + 255) / 256;
  int dbl = (E + 511) / 512;          // 2 edges/thread blocks
  float invN = 1.0f / (float)N;

  k_deg<<<dbl + 512, 256, 0, stream>>>(colv, indeg, N, E, dbl, W1, W2, Wt1, Wt2);
  k_alloc<<<nb, 256, 0, stream>>>(indeg, ctr, offs, cursor, dinv, N);
  k_scatter<<<dbl + 1024, 256, 0, stream>>>(rowv, colv, cursor, csr, N, E, dbl, x, dinv, xs, N * 32);

  k_prop_x<<<(N + 3) / 4, 256, 0, stream>>>((const unsigned int*)xs, csr, offs, indeg, dinv, (unsigned int*)sb, N);

  // stage 1: analytic BN from Gram(s), then fused GEMM->BN->PReLU->dinv -> h
  k_gram<<<dim3(XB, 1), 256, 0, stream>>>(sb, 128, 0, Gpart, m1, N);
  k_gred<<<dim3(64, 1), 256, 0, stream>>>(Gpart, G1);
  k_bnfit<<<512, 64, 0, stream>>>(W1, gamma1, beta1, G1, 0, m1, 0, scale1, shift1, invN);
  k_mm1f<<<(N + 31) / 32, 256, 0, stream>>>(sb, Wt1, scale1, shift1, alpha, dinv, h, N);

  // 512-dim propagate, split into two column halves (diagnostic + same traffic)
  k_prop_h<<<(N + 1) / 2, 256, 0, stream>>>((const unsigned int*)h, csr, offs, indeg, dinv, (unsigned int*)tb, N, 0);
  k_prop_h<<<(N + 1) / 2, 256, 0, stream>>>((const unsigned int*)h, csr, offs, indeg, dinv, (unsigned int*)tb, N, 128);

  // stage 2: per-group Gram(t), analytic BN, fused GEMM->BN->PReLU->mix->sum -> out
  k_gram<<<dim3(XB, 4), 256, 0, stream>>>(tb, 512, 128, Gpart, m2, N);
  k_gred<<<dim3(64, 4), 256, 0, stream>>>(Gpart, G2);
  k_bnfit<<<512, 64, 0, stream>>>(W2, gamma2, beta2, G2, 16384, m2, 128, scale2, shift2, invN);
  k_mm2f<<<(N + 15) / 16, 256, 0, stream>>>(tb, Wt2, scale2, shift2, alpha, mixe, out, N);
}

// Round 10
// 536.406 us; speedup vs baseline: 1.4608x; 1.0304x over previous
//
#include <hip/hip_runtime.h>
#include <stdint.h>

static constexpr float EPS = 1e-5f;
static constexpr int XB = 64;   // gram split-K partial blocks

typedef __attribute__((ext_vector_type(8))) short bfrag;
typedef __attribute__((ext_vector_type(4))) float ffrag;

__device__ __forceinline__ float bf2f(unsigned short u){
  union { unsigned int i; float f; } v; v.i = ((unsigned int)u) << 16; return v.f;
}
__device__ __forceinline__ unsigned short f2bf(float f){
  union { float f; unsigned int i; } v; v.f = f;
  unsigned int x = v.i;
  x += 0x7fffu + ((x >> 16) & 1u);   // round-to-nearest-even
  return (unsigned short)(x >> 16);
}
__device__ __forceinline__ float lo16(unsigned int v){ return bf2f((unsigned short)(v & 0xffffu)); }
__device__ __forceinline__ float hi16(unsigned int v){ return bf2f((unsigned short)(v >> 16)); }
__device__ __forceinline__ unsigned int pack2(float a, float b){
  return ((unsigned int)f2bf(b) << 16) | (unsigned int)f2bf(a);
}

// ---------------- deg (4 edges/thread, 8-slice histogram) + fused W cast ----------------
// Slice = blockIdx&7: atomics to slice s come only from blocks ≡ s (mod 8)
// (round-robin XCD heuristic) -> contention /8, no cross-slice false sharing.
__global__ __launch_bounds__(256) void k_deg(const int* __restrict__ col, int* __restrict__ indeg,
                                             int N, int E, int dbl,
                                             const float* __restrict__ W1, const float* __restrict__ W2,
                                             unsigned short* __restrict__ Wt1, unsigned short* __restrict__ Wt2){
  int b = blockIdx.x;
  if (b < dbl){
    int* hist = indeg + (size_t)(b & 7) * N;
    int e0 = (b * 256 + threadIdx.x) * 4;
    if (e0 + 4 <= E){
      int4 cc = *(const int4*)&col[e0];
      unsigned c0 = (unsigned)cc.x, c1 = (unsigned)cc.y, c2 = (unsigned)cc.z, c3 = (unsigned)cc.w;
      if (c0 < (unsigned)N) atomicAdd(&hist[c0], 1);
      if (c1 < (unsigned)N) atomicAdd(&hist[c1], 1);
      if (c2 < (unsigned)N) atomicAdd(&hist[c2], 1);
      if (c3 < (unsigned)N) atomicAdd(&hist[c3], 1);
    } else {
      for (int e = e0; e < E; e++){
        unsigned c = (unsigned)col[e];
        if (c < (unsigned)N) atomicAdd(&hist[c], 1);
      }
    }
  } else {
    int idx = (b - dbl) * 256 + threadIdx.x;   // [0, 131072)
    const float* W = W1; unsigned short* Wt = Wt1;
    if (idx >= 65536){ idx -= 65536; W = W2; Wt = Wt2; }
    int c = idx >> 7, k = idx & 127;
    int g = c >> 7, j = c & 127;
    Wt[(size_t)c * 128 + k] = f2bf(W[(size_t)g*16384 + k*128 + j]);
  }
}

// wave-scan allocation over slice-summed degrees; lays out per-slice sub-cursors.
__global__ void k_alloc(const int* __restrict__ indeg, int* __restrict__ ctr,
                        int* __restrict__ offs, int* __restrict__ cursor,
                        int* __restrict__ deg, float* __restrict__ dinv, int N){
  int tid = blockIdx.x * 256 + threadIdx.x;
  int lane = threadIdx.x & 63;
  int vs[8];
  int v = 0;
  if (tid < N){
    #pragma unroll
    for (int s = 0; s < 8; s++){ vs[s] = indeg[(size_t)s * N + tid]; v += vs[s]; }
  } else {
    #pragma unroll
    for (int s = 0; s < 8; s++) vs[s] = 0;
  }
  int incl = v;
  #pragma unroll
  for (int d = 1; d < 64; d <<= 1){
    int u = __shfl_up(incl, d);
    if (lane >= d) incl += u;
  }
  int base = 0;
  if (lane == 63) base = atomicAdd(ctr, incl);
  base = __shfl(base, 63);
  if (tid < N){
    int o = base + incl - v;
    offs[tid] = o;
    deg[tid] = v;
    int run = o;
    #pragma unroll
    for (int s = 0; s < 8; s++){ cursor[(size_t)s * N + tid] = run; run += vs[s]; }
    dinv[tid] = rsqrtf((float)(v + 1));
  }
}

// ---------------- scatter (4 edges/thread, sliced cursors) + fused xs cast ----------------
__global__ __launch_bounds__(256) void k_scatter(const int* __restrict__ row, const int* __restrict__ col,
                                                 int* __restrict__ cursor, int* __restrict__ csr,
                                                 int N, int E, int sbl,
                                                 const float* __restrict__ x, const float* __restrict__ dinv,
                                                 unsigned short* __restrict__ xs, int total4x){
  int b = blockIdx.x;
  if (b < sbl){
    int* cur = cursor + (size_t)(b & 7) * N;   // same block->edge mapping as k_deg
    int e0 = (b * 256 + threadIdx.x) * 4;
    if (e0 + 4 <= E){
      int4 cc = *(const int4*)&col[e0];
      int4 rr = *(const int4*)&row[e0];
      unsigned c0 = (unsigned)cc.x, c1 = (unsigned)cc.y, c2 = (unsigned)cc.z, c3 = (unsigned)cc.w;
      int p0 = -1, p1 = -1, p2 = -1, p3 = -1;
      if (c0 < (unsigned)N) p0 = atomicAdd(&cur[c0], 1);
      if (c1 < (unsigned)N) p1 = atomicAdd(&cur[c1], 1);
      if (c2 < (unsigned)N) p2 = atomicAdd(&cur[c2], 1);
      if (c3 < (unsigned)N) p3 = atomicAdd(&cur[c3], 1);
      if (p0 >= 0) csr[p0] = ((unsigned)rr.x < (unsigned)N) ? rr.x : 0;
      if (p1 >= 0) csr[p1] = ((unsigned)rr.y < (unsigned)N) ? rr.y : 0;
      if (p2 >= 0) csr[p2] = ((unsigned)rr.z < (unsigned)N) ? rr.z : 0;
      if (p3 >= 0) csr[p3] = ((unsigned)rr.w < (unsigned)N) ? rr.w : 0;
    } else {
      for (int e = e0; e < E; e++){
        unsigned c = (unsigned)col[e];
        if (c < (unsigned)N){
          int p = atomicAdd(&cur[c], 1);
          unsigned r = (unsigned)row[e];
          csr[p] = (r < (unsigned)N) ? (int)r : 0;
        }
      }
    }
  } else {
    int idx = (b - sbl) * 256 + threadIdx.x;
    int stride = (gridDim.x - sbl) * 256;
    for (; idx < total4x; idx += stride){
      int i = idx >> 5;
      float di = dinv[i];
      float4 v = ((const float4*)x)[idx];
      ushort4 o;
      o.x = f2bf(di * v.x); o.y = f2bf(di * v.y);
      o.z = f2bf(di * v.z); o.w = f2bf(di * v.w);
      ((ushort4*)xs)[idx] = o;
    }
  }
}

// ---------------- s = P x : 1 node/wave, 16-wide unroll ----------------
__global__ __launch_bounds__(256) void k_prop_x(const unsigned int* __restrict__ xs2,
                                               const int* __restrict__ csr,
                                               const int* __restrict__ offs, const int* __restrict__ deg,
                                               const float* __restrict__ dinv,
                                               unsigned int* __restrict__ s2, int N){
  int i = blockIdx.x * 4 + (threadIdx.x >> 6);
  if (i >= N) return;
  int c2 = threadIdx.x & 63;
  unsigned int sv = xs2[(size_t)i*64 + c2];
  float ax = lo16(sv), ay = hi16(sv);
  int e = offs[i], end = e + deg[i];
  for (; e + 16 <= end; e += 16){
    int r[16];
    #pragma unroll
    for (int j = 0; j < 16; j++) r[j] = csr[e + j];
    unsigned int v[16];
    #pragma unroll
    for (int j = 0; j < 16; j++) v[j] = xs2[(size_t)r[j]*64 + c2];
    #pragma unroll
    for (int j = 0; j < 16; j++){ ax += lo16(v[j]); ay += hi16(v[j]); }
  }
  for (; e + 4 <= end; e += 4){
    int r0 = csr[e], r1 = csr[e+1], r2 = csr[e+2], r3 = csr[e+3];
    unsigned int v0 = xs2[(size_t)r0*64 + c2], v1 = xs2[(size_t)r1*64 + c2];
    unsigned int v2 = xs2[(size_t)r2*64 + c2], v3 = xs2[(size_t)r3*64 + c2];
    ax += lo16(v0)+lo16(v1)+lo16(v2)+lo16(v3);
    ay += hi16(v0)+hi16(v1)+hi16(v2)+hi16(v3);
  }
  for (; e < end; e++){
    unsigned int v = xs2[(size_t)csr[e]*64 + c2];
    ax += lo16(v); ay += hi16(v);
  }
  float di = dinv[i];
  s2[(size_t)i*64 + c2] = pack2(di * ax, di * ay);
}

// ---------------- Gram partials + column sums over a 128-col slice (MFMA) ----------------
__global__ __launch_bounds__(256) void k_gram(const unsigned short* __restrict__ in,
                                              int rstride, int coff128,
                                              float* __restrict__ Gpart, float* __restrict__ msumbase,
                                              int N){
  int gy = blockIdx.y;
  const unsigned short* src = in + gy * coff128;
  float* Gp = Gpart + ((size_t)gy * XB + blockIdx.x) * 16384;
  float* msum = msumbase + gy * 128;

  __shared__ unsigned short st[128 * 40];
  __shared__ float colsum[128];

  int t = threadIdx.x;
  int wv = t >> 6, lane = t & 63, l16 = lane & 15, quad = lane >> 4;
  if (t < 128) colsum[t] = 0.f;

  int sn = t & 31, scb = t >> 5;

  ffrag acc[2][8];
  #pragma unroll
  for (int a = 0; a < 2; a++)
    #pragma unroll
    for (int b = 0; b < 8; b++) acc[a][b] = (ffrag){0.f,0.f,0.f,0.f};

  float cs[16];
  #pragma unroll
  for (int j = 0; j < 16; j++) cs[j] = 0.f;

  for (int c0 = blockIdx.x * 32; c0 < N; c0 += gridDim.x * 32){
    __syncthreads();
    int n = c0 + sn;
    ushort4 u0, u1, u2, u3;
    if (n < N){
      const ushort4* p = (const ushort4*)(src + (size_t)n * rstride + scb * 16);
      u0 = p[0]; u1 = p[1]; u2 = p[2]; u3 = p[3];
    } else {
      u0 = u1 = u2 = u3 = (ushort4){0,0,0,0};
    }
    unsigned short vals[16] = {u0.x,u0.y,u0.z,u0.w, u1.x,u1.y,u1.z,u1.w,
                               u2.x,u2.y,u2.z,u2.w, u3.x,u3.y,u3.z,u3.w};
    #pragma unroll
    for (int j = 0; j < 16; j++){
      st[(scb * 16 + j) * 40 + sn] = vals[j];
      cs[j] += bf2f(vals[j]);
    }
    __syncthreads();
    #pragma unroll
    for (int ta = 0; ta < 2; ta++){
      int ra = wv * 2 + ta;
      bfrag af = *(const bfrag*)&st[(ra * 16 + l16) * 40 + quad * 8];
      #pragma unroll
      for (int tb = 0; tb < 8; tb++){
        bfrag bf = *(const bfrag*)&st[(tb * 16 + l16) * 40 + quad * 8];
        acc[ta][tb] = __builtin_amdgcn_mfma_f32_16x16x32_bf16(af, bf, acc[ta][tb], 0, 0, 0);
      }
    }
  }
  #pragma unroll
  for (int j = 0; j < 16; j++) atomicAdd(&colsum[scb * 16 + j], cs[j]);
  __syncthreads();
  if (t < 128) atomicAdd(&msum[t], colsum[t]);
  #pragma unroll
  for (int ta = 0; ta < 2; ta++){
    #pragma unroll
    for (int tb = 0; tb < 8; tb++){
      int row0 = wv * 32 + ta * 16 + quad * 4;
      int colg = tb * 16 + l16;
      #pragma unroll
      for (int r = 0; r < 4; r++)
        Gp[(size_t)(row0 + r) * 128 + colg] = acc[ta][tb][r];
    }
  }
}

// ---------------- reduce gram partials ----------------
__global__ __launch_bounds__(256) void k_gred(const float* __restrict__ Gpart, float* __restrict__ G){
  int i = blockIdx.x * 256 + threadIdx.x;        // [0, 16384)
  int grp = blockIdx.y;
  const float* src = Gpart + (size_t)grp * XB * 16384;
  float s = 0.f;
  #pragma unroll 4
  for (int xb = 0; xb < XB; xb++) s += src[(size_t)xb * 16384 + i];
  G[(size_t)grp * 16384 + i] = s;
}

// ---------------- analytic BN coefficients from Gram ----------------
__global__ __launch_bounds__(64) void k_bnfit(const float* __restrict__ W,
                                              const float* __restrict__ gamma, const float* __restrict__ beta,
                                              const float* __restrict__ Gbase, int gmul,
                                              const float* __restrict__ msumbase, int mmul,
                                              float* __restrict__ scale, float* __restrict__ shiftF,
                                              float invN){
  int c = blockIdx.x;
  int g = c >> 7, j = c & 127;
  const float* Wc = W + (size_t)g * 16384 + j;
  const float* G  = Gbase + (size_t)g * gmul;
  const float* mv = msumbase + g * mmul;
  __shared__ float wl[128];
  __shared__ float ml[128];
  int t = threadIdx.x;
  for (int k = t; k < 128; k += 64){ wl[k] = Wc[(size_t)k * 128]; ml[k] = mv[k] * invN; }
  __syncthreads();
  float quad = 0.f, dm = 0.f;
  #pragma unroll
  for (int kk = 0; kk < 2; kk++){
    int k = t + kk * 64;
    float wk = wl[k];
    dm += ml[k] * wk;
    const float* Gr = G + (size_t)k * 128;
    float p = 0.f;
    for (int jj = 0; jj < 128; jj += 4){
      float4 gg = *(const float4*)(Gr + jj);
      float4 ww = *(const float4*)(wl + jj);
      p += gg.x*ww.x + gg.y*ww.y + gg.z*ww.z + gg.w*ww.w;
    }
    quad += wk * p;
  }
  for (int o = 32; o > 0; o >>= 1){
    quad += __shfl_down(quad, o);
    dm   += __shfl_down(dm, o);
  }
  if (t == 0){
    float var = quad * invN - dm * dm;
    float sc = gamma[c] * rsqrtf(var + EPS);
    scale[c] = sc;
    shiftF[c] = beta[c] - dm * sc;
  }
}

// ---------------- mm1 fused: h = dinv * prelu(BN(s @ W1)), 32 nodes/block ----------
__global__ __launch_bounds__(256) void k_mm1f(const unsigned short* __restrict__ in,
                                              const unsigned short* __restrict__ Wt,
                                              const float* __restrict__ scale, const float* __restrict__ shiftF,
                                              const float* __restrict__ alpha_p, const float* __restrict__ dinv,
                                              unsigned short* __restrict__ h, int N){
  float alpha = alpha_p[0];
  int wave = threadIdx.x >> 6, lane = threadIdx.x & 63;
  int l16 = lane & 15, quad = lane >> 4;
  int node0 = blockIdx.x * 32 + l16;
  int node1 = node0 + 16;
  int nc0 = node0 < N ? node0 : N - 1;
  int nc1 = node1 < N ? node1 : N - 1;
  int colbase0 = wave * 128;
  float di0 = dinv[nc0], di1 = dinv[nc1];

  const unsigned short* ir0 = in + (size_t)nc0 * 128 + quad * 8;
  const unsigned short* ir1 = in + (size_t)nc1 * 128 + quad * 8;
  bfrag b0a = *(const bfrag*)(ir0),      b0b = *(const bfrag*)(ir1);
  bfrag b1a = *(const bfrag*)(ir0 + 32), b1b = *(const bfrag*)(ir1 + 32);
  bfrag b2a = *(const bfrag*)(ir0 + 64), b2b = *(const bfrag*)(ir1 + 64);
  bfrag b3a = *(const bfrag*)(ir0 + 96), b3b = *(const bfrag*)(ir1 + 96);

  #pragma unroll
  for (int ct = 0; ct < 8; ct++){
    int colbase = colbase0 + ct * 16;
    const unsigned short* wrow = Wt + (size_t)(colbase + l16) * 128 + quad * 8;
    bfrag a0 = *(const bfrag*)(wrow);
    bfrag a1 = *(const bfrag*)(wrow + 32);
    bfrag a2 = *(const bfrag*)(wrow + 64);
    bfrag a3 = *(const bfrag*)(wrow + 96);
    ffrag acc0 = {0.f,0.f,0.f,0.f}, acc1 = {0.f,0.f,0.f,0.f};
    acc0 = __builtin_amdgcn_mfma_f32_16x16x32_bf16(a0, b0a, acc0, 0, 0, 0);
    acc1 = __builtin_amdgcn_mfma_f32_16x16x32_bf16(a0, b0b, acc1, 0, 0, 0);
    acc0 = __builtin_amdgcn_mfma_f32_16x16x32_bf16(a1, b1a, acc0, 0, 0, 0);
    acc1 = __builtin_amdgcn_mfma_f32_16x16x32_bf16(a1, b1b, acc1, 0, 0, 0);
    acc0 = __builtin_amdgcn_mfma_f32_16x16x32_bf16(a2, b2a, acc0, 0, 0, 0);
    acc1 = __builtin_amdgcn_mfma_f32_16x16x32_bf16(a2, b2b, acc1, 0, 0, 0);
    acc0 = __builtin_amdgcn_mfma_f32_16x16x32_bf16(a3, b3a, acc0, 0, 0, 0);
    acc1 = __builtin_amdgcn_mfma_f32_16x16x32_bf16(a3, b3b, acc1, 0, 0, 0);
    int cb = colbase + quad * 4;
    float4 sc = *(const float4*)(scale + cb);
    float4 sh = *(const float4*)(shiftF + cb);
    float v0 = acc0[0]*sc.x + sh.x; v0 = v0 > 0.f ? v0 : alpha*v0;
    float v1 = acc0[1]*sc.y + sh.y; v1 = v1 > 0.f ? v1 : alpha*v1;
    float v2 = acc0[2]*sc.z + sh.z; v2 = v2 > 0.f ? v2 : alpha*v2;
    float v3 = acc0[3]*sc.w + sh.w; v3 = v3 > 0.f ? v3 : alpha*v3;
    float w0 = acc1[0]*sc.x + sh.x; w0 = w0 > 0.f ? w0 : alpha*w0;
    float w1 = acc1[1]*sc.y + sh.y; w1 = w1 > 0.f ? w1 : alpha*w1;
    float w2 = acc1[2]*sc.z + sh.z; w2 = w2 > 0.f ? w2 : alpha*w2;
    float w3 = acc1[3]*sc.w + sh.w; w3 = w3 > 0.f ? w3 : alpha*w3;
    uint2 o0, o1;
    o0.x = pack2(di0*v0, di0*v1); o0.y = pack2(di0*v2, di0*v3);
    o1.x = pack2(di1*w0, di1*w1); o1.y = pack2(di1*w2, di1*w3);
    if (node0 < N) *(uint2*)(h + (size_t)node0 * 512 + cb) = o0;
    if (node1 < N) *(uint2*)(h + (size_t)node1 * 512 + cb) = o1;
  }
}

// ---------------- t = P h : 1 node/block, full row, 16-wide unroll ----------------
__global__ __launch_bounds__(256) void k_prop_h(const unsigned int* __restrict__ h2,
                                                const int* __restrict__ csr,
                                                const int* __restrict__ offs, const int* __restrict__ deg,
                                                const float* __restrict__ dinv,
                                                unsigned int* __restrict__ t2, int N){
  int i = blockIdx.x;
  int c2 = threadIdx.x;
  unsigned int sv = h2[(size_t)i*256 + c2];
  float ax = lo16(sv), ay = hi16(sv);
  int e = offs[i], end = e + deg[i];
  for (; e + 16 <= end; e += 16){
    int r[16];
    #pragma unroll
    for (int j = 0; j < 16; j++) r[j] = csr[e + j];
    unsigned int v[16];
    #pragma unroll
    for (int j = 0; j < 16; j++) v[j] = h2[(size_t)r[j]*256 + c2];
    #pragma unroll
    for (int j = 0; j < 16; j++){ ax += lo16(v[j]); ay += hi16(v[j]); }
  }
  for (; e + 4 <= end; e += 4){
    int r0 = csr[e], r1 = csr[e+1], r2 = csr[e+2], r3 = csr[e+3];
    unsigned int v0 = h2[(size_t)r0*256 + c2], v1 = h2[(size_t)r1*256 + c2];
    unsigned int v2 = h2[(size_t)r2*256 + c2], v3 = h2[(size_t)r3*256 + c2];
    ax += lo16(v0)+lo16(v1)+lo16(v2)+lo16(v3);
    ay += hi16(v0)+hi16(v1)+hi16(v2)+hi16(v3);
  }
  for (; e < end; e++){
    unsigned int v = h2[(size_t)csr[e]*256 + c2];
    ax += lo16(v); ay += hi16(v);
  }
  float di = dinv[i];
  t2[(size_t)i*256 + c2] = pack2(di * ax, di * ay);
}

// ---------------- mm2 fused: out = sum_g mix_g * prelu(BN(t_g @ W2_g)) ----------
__global__ __launch_bounds__(256) void k_mm2f(const unsigned short* __restrict__ t,
                                              const unsigned short* __restrict__ Wt,
                                              const float* __restrict__ scale, const float* __restrict__ shiftF,
                                              const float* __restrict__ alpha_p, const float* __restrict__ mixe,
                                              float* __restrict__ out, int N){
  __shared__ float red[4][16][132];
  float alpha = alpha_p[0];
  int wave = threadIdx.x >> 6, lane = threadIdx.x & 63;
  int l16 = lane & 15, quad = lane >> 4;
  int node = blockIdx.x * 16 + l16;
  int nc = node < N ? node : N - 1;

  float4 me = ((const float4*)mixe)[nc];
  float mx = fmaxf(fmaxf(me.x, me.y), fmaxf(me.z, me.w));
  float e0 = __expf(me.x - mx), e1 = __expf(me.y - mx), e2 = __expf(me.z - mx), e3 = __expf(me.w - mx);
  float inv = 1.f / (e0 + e1 + e2 + e3);
  float wvx = ((wave == 0) ? e0 : (wave == 1) ? e1 : (wave == 2) ? e2 : e3) * inv;

  const unsigned short* inrow = t + (size_t)nc * 512 + wave * 128 + quad * 8;
  bfrag b0 = *(const bfrag*)(inrow);
  bfrag b1 = *(const bfrag*)(inrow + 32);
  bfrag b2 = *(const bfrag*)(inrow + 64);
  bfrag b3 = *(const bfrag*)(inrow + 96);

  #pragma unroll
  for (int ct = 0; ct < 8; ct++){
    int c512 = wave * 128 + ct * 16;
    const unsigned short* wrow = Wt + (size_t)(c512 + l16) * 128 + quad * 8;
    bfrag a0 = *(const bfrag*)(wrow);
    bfrag a1 = *(const bfrag*)(wrow + 32);
    bfrag a2 = *(const bfrag*)(wrow + 64);
    bfrag a3 = *(const bfrag*)(wrow + 96);
    ffrag acc = {0.f, 0.f, 0.f, 0.f};
    acc = __builtin_amdgcn_mfma_f32_16x16x32_bf16(a0, b0, acc, 0, 0, 0);
    acc = __builtin_amdgcn_mfma_f32_16x16x32_bf16(a1, b1, acc, 0, 0, 0);
    acc = __builtin_amdgcn_mfma_f32_16x16x32_bf16(a2, b2, acc, 0, 0, 0);
    acc = __builtin_amdgcn_mfma_f32_16x16x32_bf16(a3, b3, acc, 0, 0, 0);
    int cb = c512 + quad * 4;
    float4 sc = *(const float4*)(scale + cb);
    float4 sh = *(const float4*)(shiftF + cb);
    float v0 = acc[0]*sc.x + sh.x; v0 = v0 > 0.f ? v0 : alpha*v0;
    float v1 = acc[1]*sc.y + sh.y; v1 = v1 > 0.f ? v1 : alpha*v1;
    float v2 = acc[2]*sc.z + sh.z; v2 = v2 > 0.f ? v2 : alpha*v2;
    float v3 = acc[3]*sc.w + sh.w; v3 = v3 > 0.f ? v3 : alpha*v3;
    int j = ct * 16 + quad * 4;
    float4 wr = {wvx*v0, wvx*v1, wvx*v2, wvx*v3};
    *(float4*)&red[wave][l16][j] = wr;
  }
  __syncthreads();
  int tt = threadIdx.x;
  int nn = tt >> 4, j0 = (tt & 15) * 8;
  int gnode = blockIdx.x * 16 + nn;
  if (gnode < N){
    float4 r0 = {0,0,0,0}, r1 = {0,0,0,0};
    #pragma unroll
    for (int w = 0; w < 4; w++){
      float4 p0 = *(const float4*)&red[w][nn][j0];
      float4 p1 = *(const float4*)&red[w][nn][j0 + 4];
      r0.x += p0.x; r0.y += p0.y; r0.z += p0.z; r0.w += p0.w;
      r1.x += p1.x; r1.y += p1.y; r1.z += p1.z; r1.w += p1.w;
    }
    float* op = out + (size_t)gnode * 128 + j0;
    *(float4*)(op) = r0;
    *(float4*)(op + 4) = r1;
  }
}

extern "C" void kernel_launch(void* const* d_in, const int* in_sizes, int n_in,
                              void* d_out, int out_size, void* d_ws, size_t ws_size,
                              hipStream_t stream) {
  const float* x      = (const float*)d_in[0];
  const int*   ei     = (const int*)d_in[1];
  const float* W1     = (const float*)d_in[2];
  const float* W2     = (const float*)d_in[4];
  const float* gamma1 = (const float*)d_in[6];
  const float* beta1  = (const float*)d_in[7];
  const float* gamma2 = (const float*)d_in[8];
  const float* beta2  = (const float*)d_in[9];
  const float* alpha  = (const float*)d_in[10];
  const float* mixe   = (const float*)d_in[11];
  float* out = (float*)d_out;

  const int N = in_sizes[0] / 128;
  const int E = in_sizes[1] / 2;
  const int* rowv = ei;
  const int* colv = ei + E;

  char* w = (char*)d_ws;
  size_t off = 0;
  auto take = [&](size_t bytes) -> void* {
    void* p = w + off;
    off = (off + bytes + 255) & ~(size_t)255;
    return p;
  };
  // --- zeroed region (single memset): indeg[8 slices] | ctr | m1 | m2 ---
  size_t zbeg = off;
  int*   indeg  = (int*)take((size_t)8 * N * 4);
  int*   ctr    = (int*)take(256);
  float* m1     = (float*)take(512);
  float* m2     = (float*)take(2048);
  size_t zend = off;
  // --- rest (no init needed) ---
  float* G1     = (float*)take(65536);
  float* G2     = (float*)take(262144);
  float* Gpart  = (float*)take((size_t)4 * XB * 16384 * 4);
  int*   cursor = (int*)take((size_t)8 * N * 4);
  int*   offs   = (int*)take((size_t)N * 4);
  int*   deg    = (int*)take((size_t)N * 4);
  float* dinv   = (float*)take((size_t)N * 4);
  float* scale1 = (float*)take(2048);
  float* shift1 = (float*)take(2048);
  float* scale2 = (float*)take(2048);
  float* shift2 = (float*)take(2048);
  int*   csr    = (int*)take((size_t)E * 4);
  unsigned short* Wt1 = (unsigned short*)take(512 * 128 * 2);
  unsigned short* Wt2 = (unsigned short*)take(512 * 128 * 2);
  unsigned short* xs = (unsigned short*)take((size_t)N * 128 * 2);
  unsigned short* sb = (unsigned short*)take((size_t)N * 128 * 2);
  unsigned short* h  = (unsigned short*)take((size_t)N * 512 * 2);
  unsigned short* tb = (unsigned short*)take((size_t)N * 512 * 2);

  hipMemsetAsync((char*)d_ws + zbeg, 0, zend - zbeg, stream);

  int nb  = (N + 255) / 256;
  int dbl = (E + 1023) / 1024;        // 4 edges/thread blocks
  float invN = 1.0f / (float)N;

  k_deg<<<dbl + 512, 256, 0, stream>>>(colv, indeg, N, E, dbl, W1, W2, Wt1, Wt2);
  k_alloc<<<nb, 256, 0, stream>>>(indeg, ctr, offs, cursor, deg, dinv, N);
  k_scatter<<<dbl + 1024, 256, 0, stream>>>(rowv, colv, cursor, csr, N, E, dbl, x, dinv, xs, N * 32);

  k_prop_x<<<(N + 3) / 4, 256, 0, stream>>>((const unsigned int*)xs, csr, offs, deg, dinv, (unsigned int*)sb, N);

  // stage 1: analytic BN from Gram(s), then fused GEMM->BN->PReLU->dinv -> h
  k_gram<<<dim3(XB, 1), 256, 0, stream>>>(sb, 128, 0, Gpart, m1, N);
  k_gred<<<dim3(64, 1), 256, 0, stream>>>(Gpart, G1);
  k_bnfit<<<512, 64, 0, stream>>>(W1, gamma1, beta1, G1, 0, m1, 0, scale1, shift1, invN);
  k_mm1f<<<(N + 31) / 32, 256, 0, stream>>>(sb, Wt1, scale1, shift1, alpha, dinv, h, N);

  k_prop_h<<<N, 256, 0, stream>>>((const unsigned int*)h, csr, offs, deg, dinv, (unsigned int*)tb, N);

  // stage 2: per-group Gram(t), analytic BN, fused GEMM->BN->PReLU->mix->sum -> out
  k_gram<<<dim3(XB, 4), 256, 0, stream>>>(tb, 512, 128, Gpart, m2, N);
  k_gred<<<dim3(64, 4), 256, 0, stream>>>(Gpart, G2);
  k_bnfit<<<512, 64, 0, stream>>>(W2, gamma2, beta2, G2, 16384, m2, 128, scale2, shift2, invN);
  k_mm2f<<<(N + 15) / 16, 256, 0, stream>>>(tb, Wt2, scale2, shift2, alpha, mixe, out, N);
}